// Round 19
// baseline (391.225 us; speedup 1.0000x reference)
//
#include <hip/hip_runtime.h>
#include <stdint.h>

typedef __bf16 bf16x8 __attribute__((ext_vector_type(8)));
typedef float f32x4 __attribute__((ext_vector_type(4)));

#define LOG2E 1.4426950408889634f
#define LSTR 32  // LDS row stride in shorts (64 B); required by global_load_lds scatter

__device__ __forceinline__ unsigned short f2bf(float f) {
  unsigned int x = __builtin_bit_cast(unsigned int, f);
  x += 0x7FFFu + ((x >> 16) & 1u);
  return (unsigned short)(x >> 16);
}
__device__ __forceinline__ float bflo(unsigned int u) {
  return __builtin_bit_cast(float, u << 16);
}
__device__ __forceinline__ float bfhi(unsigned int u) {
  return __builtin_bit_cast(float, u & 0xffff0000u);
}
__device__ __forceinline__ float tanh_fast(float x) {
  float cx = fminf(fmaxf(x, -15.f), 15.f);
  float e = __builtin_amdgcn_exp2f(cx * (2.f * LOG2E));   // e^(2x)
  return (e - 1.f) * __builtin_amdgcn_rcpf(e + 1.f);
}
__device__ __forceinline__ float sigmoid_fast(float x) {
  float cx = fminf(fmaxf(x, -30.f), 30.f);
  float e = __builtin_amdgcn_exp2f(cx * LOG2E);           // e^x
  return e * __builtin_amdgcn_rcpf(e + 1.f);
}
__device__ __forceinline__ ushort4 cvt4(const float4 f) {
  return make_ushort4(f2bf(f.x), f2bf(f.y), f2bf(f.z), f2bf(f.w));
}
__device__ __forceinline__ float4 f4(const f32x4 v) {
  return make_float4(v[0], v[1], v[2], v[3]);
}

// async global->LDS, 16B/lane; LDS dest = wave-uniform base + lane*16.
__device__ __forceinline__ void gl_lds16(const unsigned short* g,
                                         const unsigned short* lds_base) {
  __builtin_amdgcn_global_load_lds(
      (const __attribute__((address_space(1))) unsigned int*)(uintptr_t)g,
      (__attribute__((address_space(3))) unsigned int*)(unsigned int)(uintptr_t)lds_base,
      16, 0, 0);
}

// ---------------------------------------------------------------------------
// 0) Fused prep (R17-measured best): [0,256) W_enc transpose->bf16 |
//    [256,768) dvec | [768,800) zero scoresb | [800,17184) enc fp32->bf16.
//    Conv: NT LOADS ONLY (R16/R17 A/B: nt-load kills the 128 MB read's cache
//    pollution; REGULAR stores keep encb warm for scores).
// ---------------------------------------------------------------------------
__global__ __launch_bounds__(256) void k_prep(
    const float* __restrict__ W_enc, unsigned short* __restrict__ Wt,
    const float* __restrict__ states, const float* __restrict__ W_dec,
    const float* __restrict__ b_dec, const float* __restrict__ b_enc,
    float* __restrict__ dvec, float4* __restrict__ zbase,
    const float* __restrict__ enc, unsigned short* __restrict__ encb) {
  __shared__ unsigned short tile[64][65];
  __shared__ float red[256];
  const int bid = blockIdx.x;
  const int tid = threadIdx.x;
  if (bid < 256) {            // ---- transpose W_enc -> Wt (bf16)
    const int bx = bid & 15, by = bid >> 4;
    const int x = tid & 63, y0 = tid >> 6;
#pragma unroll
    for (int i = y0; i < 64; i += 4)
      tile[i][x] = f2bf(W_enc[(size_t)(by * 64 + i) * 1024 + bx * 64 + x]);
    __syncthreads();
#pragma unroll
    for (int i = y0; i < 64; i += 4)
      Wt[(size_t)(bx * 64 + i) * 1024 + by * 64 + x] = tile[x][i];
  } else if (bid < 768) {     // ---- dvec
    const int bb = bid - 256;
    const int b = bb >> 3;
    const int a0 = (bb & 7) * 128;
    const int a = tid & 127, half = tid >> 7;
    const float* sp = states + (size_t)b * 1024;
    const float* wp = W_dec + a0 + a;
    float acc = 0.f;
    const int kb = half * 512;
#pragma unroll 8
    for (int k = kb; k < kb + 512; ++k)
      acc += sp[k] * wp[(size_t)k * 1024];
    red[tid] = acc;
    __syncthreads();
    if (tid < 128) {
      float v = red[tid] + red[tid + 128];
      dvec[(size_t)b * 1024 + a0 + tid] = v + b_dec[a0 + tid] + b_enc[a0 + tid];
    }
  } else if (bid < 800) {     // ---- zero scoresb (128 KB)
    const float4 z = {0.f, 0.f, 0.f, 0.f};
    zbase[(size_t)(bid - 768) * 256 + tid] = z;
  } else {                    // ---- enc fp32 -> bf16 (nt load, regular store)
    const size_t i = ((size_t)(bid - 800) * 256 + tid) * 8;
    const f32x4 f0 = __builtin_nontemporal_load((const f32x4*)(enc + i));
    const f32x4 f1 = __builtin_nontemporal_load((const f32x4*)(enc + i + 4));
    *(ushort4*)(encb + i) = cvt4(f4(f0));
    *(ushort4*)(encb + i + 4) = cvt4(f4(f1));
  }
}

// ---------------------------------------------------------------------------
// 3a) Fused scores, bf16 (R6/R17 winner) + v6: __launch_bounds__(256,4).
//     Resources fit 4 blocks/CU (LDS 33.28KB x4 = 133KB <= 160KB; 64 arch
//     VGPR + 64 acc = 128 = exactly the 4-wave/SIMD budget). The 2-barrier
//     schedule's drain stall is block-internal; more co-resident BLOCKS
//     interleave their barriers (m114 overlap). 3->4 = +33% overlap capacity.
// ---------------------------------------------------------------------------
__global__ __launch_bounds__(256, 4) void k_scores_bf16(
    const unsigned short* __restrict__ encb,  // [32768][1024] bf16
    const unsigned short* __restrict__ Wt,    // [1024 a][1024 h] bf16
    const float* __restrict__ dvec,           // [64][1024]
    const float* __restrict__ w_out,          // [1024]
    float* __restrict__ scores) {             // [64][512], pre-zeroed
  __shared__ alignas(16) unsigned short lds[2][8192];  // 2 x (A 8KB | B 8KB)
  __shared__ float sc[128];

  const int tid = threadIdx.x;
  const int wave = tid >> 6, lane = tid & 63;
  const int l15 = lane & 15, quad = lane >> 4;
  const int xcd = blockIdx.x & 7;          // HW: XCD = blockIdx % 8
  const int kb_ = blockIdx.x >> 3;
  const int mt = ((kb_ >> 3) << 3) | xcd;  // same-mt blocks -> same XCD
  const int nt = kb_ & 7;
  const int row0 = mt * 128;
  const int b = row0 >> 9;
  const int wm = (wave >> 1) * 64, wn = (wave & 1) * 64;
  const int srow = lane >> 2;         // 0..15 within staging region
  const int fsw = ((lane >> 2) & 3) ^ ((lane >> 4) & 3);
  const int skoff = (((lane & 3) ^ fsw) * 8);
  const int rchunk = ((quad ^ ((l15 & 3) ^ ((l15 >> 2) & 3))) * 8);

  if (tid < 128) sc[tid] = 0.f;

  const unsigned short* gsrc[4];
#pragma unroll
  for (int s = 0; s < 4; ++s) {
    const int g = wave * 4 + s;
    gsrc[s] = (g < 8)
        ? encb + (size_t)(row0 + g * 16 + srow) * 1024 + skoff
        : Wt + (size_t)(nt * 128 + (g - 8) * 16 + srow) * 1024 + skoff;
  }

  const f32x4 vz = {0.f, 0.f, 0.f, 0.f};
  f32x4 acc[4][4];
#pragma unroll
  for (int i = 0; i < 4; ++i)
#pragma unroll
    for (int j = 0; j < 4; ++j) acc[i][j] = vz;

#define STAGE(BUF, KK)                                              \
  do {                                                              \
    _Pragma("unroll") for (int s = 0; s < 4; ++s)                   \
        gl_lds16(gsrc[s] + (KK), &lds[BUF][(wave * 4 + s) * 512]);  \
  } while (0)

#define COMPUTE(BUF)                                                          \
  do {                                                                        \
    bf16x8 af[4], bg[4];                                                      \
    _Pragma("unroll") for (int i = 0; i < 4; ++i)                             \
        af[i] = *(const bf16x8*)(&lds[BUF][(wm + i * 16 + l15) * LSTR + rchunk]); \
    _Pragma("unroll") for (int j = 0; j < 4; ++j)                             \
        bg[j] = *(const bf16x8*)(&lds[BUF][4096 + (wn + j * 16 + l15) * LSTR + rchunk]); \
    _Pragma("unroll") for (int i = 0; i < 4; ++i)                             \
      _Pragma("unroll") for (int j = 0; j < 4; ++j)                           \
          acc[i][j] = __builtin_amdgcn_mfma_f32_16x16x32_bf16(af[i], bg[j],   \
                                                              acc[i][j], 0, 0, 0); \
  } while (0)

  STAGE(0, 0);
  __syncthreads();

#pragma unroll 1
  for (int k0 = 0; k0 < 1024; k0 += 64) {
    STAGE(1, k0 + 32);
    COMPUTE(0);
    __syncthreads();
    if (k0 + 64 < 1024) { STAGE(0, k0 + 64); }
    COMPUTE(1);
    __syncthreads();
  }
#undef STAGE
#undef COMPUTE

  float p[4][4];
#pragma unroll
  for (int i = 0; i < 4; ++i)
#pragma unroll
    for (int r = 0; r < 4; ++r) p[i][r] = 0.f;
#pragma unroll
  for (int j = 0; j < 4; ++j) {
    const int a = nt * 128 + wn + j * 16 + l15;
    const float dv = dvec[(size_t)b * 1024 + a];
    const float wo = w_out[a];
#pragma unroll
    for (int i = 0; i < 4; ++i)
#pragma unroll
      for (int r = 0; r < 4; ++r)
        p[i][r] += tanh_fast(acc[i][j][r] + dv) * wo;
  }
#pragma unroll
  for (int i = 0; i < 4; ++i)
#pragma unroll
    for (int r = 0; r < 4; ++r) {
      float v = p[i][r];
      v += __shfl_xor(v, 1);
      v += __shfl_xor(v, 2);
      v += __shfl_xor(v, 4);
      v += __shfl_xor(v, 8);
      if (l15 == 0) atomicAdd(&sc[wm + i * 16 + quad * 4 + r], v);
    }
  __syncthreads();
  if (tid < 128)
    atomicAdd(&scores[(size_t)b * 512 + (row0 & 511) + tid], sc[tid]);
}

// ---------------------------------------------------------------------------
// 3b) fp32 fallback (unchanged)
// ---------------------------------------------------------------------------
__global__ __launch_bounds__(256) void k_scores_f32(
    const float* __restrict__ enc, const unsigned short* __restrict__ Wt,
    const float* __restrict__ dvec, const float* __restrict__ w_out,
    float* __restrict__ scores) {
  __shared__ alignas(16) unsigned short lA[128 * LSTR];
  __shared__ alignas(16) unsigned short lB[128 * LSTR];
  __shared__ float sc[128];
  const int tid = threadIdx.x;
  const int wave = tid >> 6, lane = tid & 63;
  const int l15 = lane & 15, quad = lane >> 4;
  const int mt = blockIdx.x >> 2, nh = blockIdx.x & 3;
  const int row0 = mt * 128, b = row0 >> 9;
  const int wm = (wave >> 1) * 64, wn = (wave & 1) * 64;
  const int srow = lane >> 2, skoff = (lane & 3) * 8;
  if (tid < 128) sc[tid] = 0.f;
  const f32x4 vz = {0.f, 0.f, 0.f, 0.f};
#pragma unroll 1
  for (int t2 = 0; t2 < 2; ++t2) {
    const int nt = nh * 2 + t2;
    f32x4 acc[4][4];
#pragma unroll
    for (int i = 0; i < 4; ++i)
#pragma unroll
      for (int j = 0; j < 4; ++j) acc[i][j] = vz;
#pragma unroll 1
    for (int k0 = 0; k0 < 1024; k0 += 32) {
      ushort4 sa[2][2];
      uint4 vb[2];
#pragma unroll
      for (int rr = 0; rr < 2; ++rr) {
        const int r = wave * 2 + rr;
        const float* ap = enc + (size_t)(row0 + r * 16 + srow) * 1024 + k0 + skoff;
        sa[rr][0] = cvt4(*(const float4*)ap);
        sa[rr][1] = cvt4(*(const float4*)(ap + 4));
        vb[rr] = *(const uint4*)(Wt + (size_t)(nt * 128 + r * 16 + srow) * 1024 + k0 + skoff);
      }
      __syncthreads();
#pragma unroll
      for (int rr = 0; rr < 2; ++rr) {
        const int r = wave * 2 + rr;
        *(ushort4*)(lA + (r * 16 + srow) * LSTR + skoff) = sa[rr][0];
        *(ushort4*)(lA + (r * 16 + srow) * LSTR + skoff + 4) = sa[rr][1];
        *(uint4*)(lB + (r * 16 + srow) * LSTR + skoff) = vb[rr];
      }
      __syncthreads();
      bf16x8 af[4], bg[4];
#pragma unroll
      for (int i = 0; i < 4; ++i)
        af[i] = *(const bf16x8*)(lA + (wm + i * 16 + l15) * LSTR + quad * 8);
#pragma unroll
      for (int j = 0; j < 4; ++j)
        bg[j] = *(const bf16x8*)(lB + (wn + j * 16 + l15) * LSTR + quad * 8);
#pragma unroll
      for (int i = 0; i < 4; ++i)
#pragma unroll
        for (int j = 0; j < 4; ++j)
          acc[i][j] = __builtin_amdgcn_mfma_f32_16x16x32_bf16(af[i], bg[j],
                                                              acc[i][j], 0, 0, 0);
    }
    float p[4][4];
#pragma unroll
    for (int i = 0; i < 4; ++i)
#pragma unroll
      for (int r = 0; r < 4; ++r) p[i][r] = 0.f;
#pragma unroll
    for (int j = 0; j < 4; ++j) {
      const int a = nt * 128 + wn + j * 16 + l15;
      const float dv = dvec[(size_t)b * 1024 + a];
      const float wo = w_out[a];
#pragma unroll
      for (int i = 0; i < 4; ++i)
#pragma unroll
        for (int r = 0; r < 4; ++r)
          p[i][r] += tanh_fast(acc[i][j][r] + dv) * wo;
    }
#pragma unroll
    for (int i = 0; i < 4; ++i)
#pragma unroll
      for (int r = 0; r < 4; ++r) {
        float v = p[i][r];
        v += __shfl_xor(v, 1);
        v += __shfl_xor(v, 2);
        v += __shfl_xor(v, 4);
        v += __shfl_xor(v, 8);
        if (l15 == 0) atomicAdd(&sc[wm + i * 16 + quad * 4 + r], v);
      }
  }
  __syncthreads();
  if (tid < 128)
    atomicAdd(&scores[(size_t)b * 512 + (row0 & 511) + tid], sc[tid]);
}

// ---------------------------------------------------------------------------
// 4) attn (R9/R17-measured): grid 1024 = 64 b x 8 hch x 2 s-halves.
//    Full softmax per block (cheap, redundant), GEMV over 256-s half x 128-h
//    slice, writes partial plane att2[sh][b][h]. No atomics.
// ---------------------------------------------------------------------------
template <bool ABF16>
__global__ __launch_bounds__(256) void k_attn(const void* __restrict__ encv,
                                              const float* __restrict__ scores,
                                              float* __restrict__ att2) {
  const int b = blockIdx.x >> 4;
  const int hch = (blockIdx.x >> 1) & 7;
  const int sh = blockIdx.x & 1;
  const int tid = threadIdx.x;
  __shared__ float w[512];
  __shared__ float redm[4], reds[4];
  __shared__ float red[16][132];   // +4 pad

  const float s0 = scores[(size_t)b * 512 + tid];
  const float s1 = scores[(size_t)b * 512 + 256 + tid];
  float m = fmaxf(s0, s1);
#pragma unroll
  for (int off = 32; off; off >>= 1) m = fmaxf(m, __shfl_xor(m, off));
  const int wv = tid >> 6;
  if ((tid & 63) == 0) redm[wv] = m;
  __syncthreads();
  m = fmaxf(fmaxf(redm[0], redm[1]), fmaxf(redm[2], redm[3]));
  const float e0 = __builtin_amdgcn_exp2f((s0 - m) * LOG2E);
  const float e1 = __builtin_amdgcn_exp2f((s1 - m) * LOG2E);
  float sum = e0 + e1;
#pragma unroll
  for (int off = 32; off; off >>= 1) sum += __shfl_xor(sum, off);
  if ((tid & 63) == 0) reds[wv] = sum;
  __syncthreads();
  sum = reds[0] + reds[1] + reds[2] + reds[3];
  const float inv = 1.f / sum;
  w[tid] = e0 * inv;
  w[tid + 256] = e1 * inv;
  __syncthreads();

  const int sgrp = tid >> 4;        // 0..15
  const int hsub = tid & 15;        // 0..15
  const int h0 = hch * 128 + hsub * 8;
  float a[8];
#pragma unroll
  for (int j = 0; j < 8; ++j) a[j] = 0.f;
#pragma unroll 8
  for (int si = 0; si < 16; ++si) {
    const int s = sh * 256 + si * 16 + sgrp;
    const float ws_ = w[s];
    if constexpr (ABF16) {
      const uint4 v = *(const uint4*)((const unsigned short*)encv +
                                      (size_t)(b * 512 + s) * 1024 + h0);
      a[0] += ws_ * bflo(v.x); a[1] += ws_ * bfhi(v.x);
      a[2] += ws_ * bflo(v.y); a[3] += ws_ * bfhi(v.y);
      a[4] += ws_ * bflo(v.z); a[5] += ws_ * bfhi(v.z);
      a[6] += ws_ * bflo(v.w); a[7] += ws_ * bfhi(v.w);
    } else {
      const float* ep = (const float*)encv + (size_t)(b * 512 + s) * 1024 + h0;
      const float4 v0 = *(const float4*)ep;
      const float4 v1 = *(const float4*)(ep + 4);
      a[0] += ws_ * v0.x; a[1] += ws_ * v0.y;
      a[2] += ws_ * v0.z; a[3] += ws_ * v0.w;
      a[4] += ws_ * v1.x; a[5] += ws_ * v1.y;
      a[6] += ws_ * v1.z; a[7] += ws_ * v1.w;
    }
  }
#pragma unroll
  for (int j = 0; j < 8; ++j) red[sgrp][hsub * 8 + j] = a[j];
  __syncthreads();
#pragma unroll
  for (int step = 8; step >= 1; step >>= 1) {
    if (sgrp < step) {
#pragma unroll
      for (int j = 0; j < 8; ++j)
        red[sgrp][hsub * 8 + j] += red[sgrp + step][hsub * 8 + j];
    }
    __syncthreads();
  }
  if (sgrp == 0) {
    float* op = att2 + ((size_t)sh * 64 + b) * 1024 + h0;
    float4 o0 = {red[0][hsub * 8 + 0], red[0][hsub * 8 + 1],
                 red[0][hsub * 8 + 2], red[0][hsub * 8 + 3]};
    float4 o1 = {red[0][hsub * 8 + 4], red[0][hsub * 8 + 5],
                 red[0][hsub * 8 + 6], red[0][hsub * 8 + 7]};
    *(float4*)op = o0;
    *(float4*)(op + 4) = o1;
  }
}

// ---------------------------------------------------------------------------
// 5) GRU gemms (R9/R17-measured): K-eighths, grid 768, 16 partial planes.
// ---------------------------------------------------------------------------
__global__ __launch_bounds__(256) void k_gru_gemm(
    const float* __restrict__ xin,    // [64][1024]
    const float* __restrict__ att2,   // [2][64][1024] partial planes
    const float* __restrict__ states, // [64][1024]
    const float* __restrict__ W_ih,   // [3072][2048]
    const float* __restrict__ W_hh,   // [3072][1024]
    float* __restrict__ gbuf) {       // [16][64][3072] partial planes
  const int tid = threadIdx.x;
  const int wave = tid >> 6, lane = tid & 63;
  const int l15 = lane & 15, quad = lane >> 4;
  const int kk = blockIdx.x & 7;
  const int rest = blockIdx.x >> 3;   // 0..95
  const bool is_gh = rest >= 48;
  const int nt = is_gh ? rest - 48 : rest;
  const int n0 = nt * 64;
  const int KT = is_gh ? 1024 : 2048;
  const int Kh = KT >> 3;             // eighth
  const int kbase = kk * Kh;
  const float* W = is_gh ? W_hh : W_ih;
  const int plane = is_gh ? 8 + kk : kk;
  float* outp = gbuf + (size_t)plane * 64 * 3072;

  __shared__ alignas(16) unsigned short lA[64 * LSTR];
  __shared__ alignas(16) unsigned short lB[64 * LSTR];

  const f32x4 vz = {0.f, 0.f, 0.f, 0.f};
  f32x4 acc[2][2];
  acc[0][0] = vz; acc[0][1] = vz; acc[1][0] = vz; acc[1][1] = vz;

  const int arow = tid >> 2;          // 0..63
  const int achunk = (tid & 3) * 8;   // global chunk (unswizzled)
  const int fswG = ((tid >> 2) & 3) ^ ((tid >> 4) & 3);
  const int wchunk = (((tid & 3) ^ fswG) * 8);
  const int rchunkG = ((quad ^ ((l15 & 3) ^ ((l15 >> 2) & 3))) * 8);
  const int wm2 = (wave >> 1) * 32, wn2 = (wave & 1) * 32;

  float4 ra0, ra1, rb0, rb1;
  auto LOADK = [&](int kg0) {
    const int kg = kg0 + achunk;
    if (is_gh) {
      const float* ap = states + (size_t)arow * 1024 + kg;
      ra0 = *(const float4*)ap;
      ra1 = *(const float4*)(ap + 4);
    } else if (kg < 1024) {
      const float* ap = xin + (size_t)arow * 1024 + kg;
      ra0 = *(const float4*)ap;
      ra1 = *(const float4*)(ap + 4);
    } else {
      const float* p0 = att2 + (size_t)arow * 1024 + (kg - 1024);
      const float* p1 = p0 + (size_t)64 * 1024;
      const float4 x0 = *(const float4*)p0, y0 = *(const float4*)p1;
      const float4 x1 = *(const float4*)(p0 + 4), y1 = *(const float4*)(p1 + 4);
      ra0 = make_float4(x0.x + y0.x, x0.y + y0.y, x0.z + y0.z, x0.w + y0.w);
      ra1 = make_float4(x1.x + y1.x, x1.y + y1.y, x1.z + y1.z, x1.w + y1.w);
    }
    const float* wp = W + (size_t)(n0 + arow) * KT + kg;
    rb0 = *(const float4*)wp;
    rb1 = *(const float4*)(wp + 4);
  };
  LOADK(kbase);

#pragma unroll 1
  for (int k0 = 0; k0 < Kh; k0 += 32) {
    __syncthreads();
    *(ushort4*)(lA + arow * LSTR + wchunk) = cvt4(ra0);
    *(ushort4*)(lA + arow * LSTR + wchunk + 4) = cvt4(ra1);
    *(ushort4*)(lB + arow * LSTR + wchunk) = cvt4(rb0);
    *(ushort4*)(lB + arow * LSTR + wchunk + 4) = cvt4(rb1);
    __syncthreads();
    if (k0 + 32 < Kh) LOADK(kbase + k0 + 32);  // issue early; MFMA covers latency
    bf16x8 af[2], bg[2];
#pragma unroll
    for (int i = 0; i < 2; ++i)
      af[i] = *(const bf16x8*)(lA + (wm2 + i * 16 + l15) * LSTR + rchunkG);
#pragma unroll
    for (int j = 0; j < 2; ++j)
      bg[j] = *(const bf16x8*)(lB + (wn2 + j * 16 + l15) * LSTR + rchunkG);
#pragma unroll
    for (int i = 0; i < 2; ++i)
#pragma unroll
      for (int j = 0; j < 2; ++j)
        acc[i][j] = __builtin_amdgcn_mfma_f32_16x16x32_bf16(af[i], bg[j],
                                                            acc[i][j], 0, 0, 0);
  }
#pragma unroll
  for (int i = 0; i < 2; ++i)
#pragma unroll
    for (int j = 0; j < 2; ++j)
#pragma unroll
      for (int r = 0; r < 4; ++r) {
        const int m = wm2 + i * 16 + quad * 4 + r;
        const int n = n0 + wn2 + j * 16 + l15;
        outp[(size_t)m * 3072 + n] = acc[i][j][r];
      }
}

// ---------------------------------------------------------------------------
// 6) gates: sum 8 gi-planes + 8 gh-planes -> output fp32
// ---------------------------------------------------------------------------
__global__ void k_gate(const float* __restrict__ gbuf,
                       const float* __restrict__ states,
                       const float* __restrict__ b_ih,
                       const float* __restrict__ b_hh,
                       float* __restrict__ outp) {
  const int idx = blockIdx.x * 256 + threadIdx.x;  // 0..65535
  const int b = idx >> 10, h = idx & 1023;
  float gir = 0.f, giz = 0.f, gin = 0.f, ghr = 0.f, ghz = 0.f, ghn = 0.f;
#pragma unroll
  for (int p = 0; p < 8; ++p) {
    const float* gi = gbuf + ((size_t)p * 64 + b) * 3072;
    gir += gi[h]; giz += gi[1024 + h]; gin += gi[2048 + h];
    const float* gh = gbuf + ((size_t)(8 + p) * 64 + b) * 3072;
    ghr += gh[h]; ghz += gh[1024 + h]; ghn += gh[2048 + h];
  }
  const float ir = gir + b_ih[h];
  const float iz = giz + b_ih[1024 + h];
  const float in_ = gin + b_ih[2048 + h];
  const float hr = ghr + b_hh[h];
  const float hz = ghz + b_hh[1024 + h];
  const float hn = ghn + b_hh[2048 + h];
  const float r = sigmoid_fast(ir + hr);
  const float z = sigmoid_fast(iz + hz);
  const float n = tanh_fast(in_ + r * hn);
  const float hp = states[idx];
  outp[idx] = (1.f - z) * n + z * hp;
}

// ---------------------------------------------------------------------------
extern "C" void kernel_launch(void* const* d_in, const int* in_sizes, int n_in,
                              void* d_out, int out_size, void* d_ws, size_t ws_size,
                              hipStream_t stream) {
  const float* enc    = (const float*)d_in[0];
  const float* xin    = (const float*)d_in[1];
  const float* states = (const float*)d_in[2];
  const float* W_enc  = (const float*)d_in[3];
  const float* b_enc  = (const float*)d_in[4];
  const float* W_dec  = (const float*)d_in[5];
  const float* b_dec  = (const float*)d_in[6];
  const float* w_out  = (const float*)d_in[7];
  // d_in[8] = b_out: softmax-shift-invariant, unused exactly.
  const float* W_ih   = (const float*)d_in[9];
  const float* W_hh   = (const float*)d_in[10];
  const float* b_ih   = (const float*)d_in[11];
  const float* b_hh   = (const float*)d_in[12];
  float* out = (float*)d_out;

  const size_t ENC_BF16_BYTES = (size_t)32768 * 1024 * 2;  // 64 MB
  const bool use_bf16 = ws_size >= ENC_BF16_BYTES + (8u << 20);

  char* ws = (char*)d_ws;
  unsigned short* encb = (unsigned short*)ws;              // 64 MB (bf16 path)
  char* base = ws + (use_bf16 ? ENC_BF16_BYTES : 0);
  unsigned short* Wt = (unsigned short*)base;              // 2 MB (bf16)
  float* dvec    = (float*)(base + 2097152);               // 256 KB
  float* scoresb = (float*)(base + 2097152 + 262144);      // 128 KB (zeroed)
  float* att2    = (float*)(base + 2097152 + 262144 + 131072);  // 512 KB (2 planes)
  // gbuf [16][64][3072] fp32 = 12.6 MB. bf16 path: OVERLAY encb region (gru
  // runs after attn, the last encb reader; prep rewrites encb each iteration).
  float* gbuf = use_bf16 ? (float*)ws : (float*)(base + (4u << 20));

  const int prep_grid = use_bf16 ? 17184 : 800;
  k_prep<<<prep_grid, 256, 0, stream>>>(W_enc, Wt, states, W_dec, b_dec, b_enc,
                                        dvec, (float4*)scoresb, enc, encb);
  if (use_bf16) {
    k_scores_bf16<<<2048, 256, 0, stream>>>(encb, Wt, dvec, w_out, scoresb);
    k_attn<true><<<1024, 256, 0, stream>>>(encb, scoresb, att2);
  } else {
    k_scores_f32<<<1024, 256, 0, stream>>>(enc, Wt, dvec, w_out, scoresb);
    k_attn<false><<<1024, 256, 0, stream>>>(enc, scoresb, att2);
  }
  k_gru_gemm<<<768, 256, 0, stream>>>(xin, att2, states, W_ih, W_hh, gbuf);
  k_gate<<<256, 256, 0, stream>>>(gbuf, states, b_ih, b_hh, out);
}

// Round 20
// 382.922 us; speedup vs baseline: 1.0217x; 1.0217x over previous
//
#include <hip/hip_runtime.h>
#include <stdint.h>

typedef __bf16 bf16x8 __attribute__((ext_vector_type(8)));
typedef float f32x4 __attribute__((ext_vector_type(4)));

#define LOG2E 1.4426950408889634f
#define LSTR 32  // LDS row stride in shorts (64 B); required by global_load_lds scatter

__device__ __forceinline__ unsigned short f2bf(float f) {
  unsigned int x = __builtin_bit_cast(unsigned int, f);
  x += 0x7FFFu + ((x >> 16) & 1u);
  return (unsigned short)(x >> 16);
}
__device__ __forceinline__ float bflo(unsigned int u) {
  return __builtin_bit_cast(float, u << 16);
}
__device__ __forceinline__ float bfhi(unsigned int u) {
  return __builtin_bit_cast(float, u & 0xffff0000u);
}
__device__ __forceinline__ float tanh_fast(float x) {
  float cx = fminf(fmaxf(x, -15.f), 15.f);
  float e = __builtin_amdgcn_exp2f(cx * (2.f * LOG2E));   // e^(2x)
  return (e - 1.f) * __builtin_amdgcn_rcpf(e + 1.f);
}
__device__ __forceinline__ float sigmoid_fast(float x) {
  float cx = fminf(fmaxf(x, -30.f), 30.f);
  float e = __builtin_amdgcn_exp2f(cx * LOG2E);           // e^x
  return e * __builtin_amdgcn_rcpf(e + 1.f);
}
__device__ __forceinline__ ushort4 cvt4(const float4 f) {
  return make_ushort4(f2bf(f.x), f2bf(f.y), f2bf(f.z), f2bf(f.w));
}
__device__ __forceinline__ float4 f4(const f32x4 v) {
  return make_float4(v[0], v[1], v[2], v[3]);
}

// async global->LDS, 16B/lane; LDS dest = wave-uniform base + lane*16.
__device__ __forceinline__ void gl_lds16(const unsigned short* g,
                                         const unsigned short* lds_base) {
  __builtin_amdgcn_global_load_lds(
      (const __attribute__((address_space(1))) unsigned int*)(uintptr_t)g,
      (__attribute__((address_space(3))) unsigned int*)(unsigned int)(uintptr_t)lds_base,
      16, 0, 0);
}

// ---------------------------------------------------------------------------
// 0) Fused prep (R17-measured best): [0,256) W_enc transpose->bf16 |
//    [256,768) dvec | [768,800) zero scoresb | [800,17184) enc fp32->bf16.
//    Conv: NT LOADS ONLY (R16/R17 A/B: nt-load kills the 128 MB read's cache
//    pollution; REGULAR stores keep encb warm for scores). Stream rule:
//    single-read streams must not allocate; consumer-bound streams must.
// ---------------------------------------------------------------------------
__global__ __launch_bounds__(256) void k_prep(
    const float* __restrict__ W_enc, unsigned short* __restrict__ Wt,
    const float* __restrict__ states, const float* __restrict__ W_dec,
    const float* __restrict__ b_dec, const float* __restrict__ b_enc,
    float* __restrict__ dvec, float4* __restrict__ zbase,
    const float* __restrict__ enc, unsigned short* __restrict__ encb) {
  __shared__ unsigned short tile[64][65];
  __shared__ float red[256];
  const int bid = blockIdx.x;
  const int tid = threadIdx.x;
  if (bid < 256) {            // ---- transpose W_enc -> Wt (bf16)
    const int bx = bid & 15, by = bid >> 4;
    const int x = tid & 63, y0 = tid >> 6;
#pragma unroll
    for (int i = y0; i < 64; i += 4)
      tile[i][x] = f2bf(W_enc[(size_t)(by * 64 + i) * 1024 + bx * 64 + x]);
    __syncthreads();
#pragma unroll
    for (int i = y0; i < 64; i += 4)
      Wt[(size_t)(bx * 64 + i) * 1024 + by * 64 + x] = tile[x][i];
  } else if (bid < 768) {     // ---- dvec
    const int bb = bid - 256;
    const int b = bb >> 3;
    const int a0 = (bb & 7) * 128;
    const int a = tid & 127, half = tid >> 7;
    const float* sp = states + (size_t)b * 1024;
    const float* wp = W_dec + a0 + a;
    float acc = 0.f;
    const int kb = half * 512;
#pragma unroll 8
    for (int k = kb; k < kb + 512; ++k)
      acc += sp[k] * wp[(size_t)k * 1024];
    red[tid] = acc;
    __syncthreads();
    if (tid < 128) {
      float v = red[tid] + red[tid + 128];
      dvec[(size_t)b * 1024 + a0 + tid] = v + b_dec[a0 + tid] + b_enc[a0 + tid];
    }
  } else if (bid < 800) {     // ---- zero scoresb (128 KB)
    const float4 z = {0.f, 0.f, 0.f, 0.f};
    zbase[(size_t)(bid - 768) * 256 + tid] = z;
  } else {                    // ---- enc fp32 -> bf16 (nt load, regular store)
    const size_t i = ((size_t)(bid - 800) * 256 + tid) * 8;
    const f32x4 f0 = __builtin_nontemporal_load((const f32x4*)(enc + i));
    const f32x4 f1 = __builtin_nontemporal_load((const f32x4*)(enc + i + 4));
    *(ushort4*)(encb + i) = cvt4(f4(f0));
    *(ushort4*)(encb + i + 4) = cvt4(f4(f1));
  }
}

// ---------------------------------------------------------------------------
// 3a) Fused scores, bf16 (R6/R17-measured winner: 128x128 tile, 2-phase dbuf,
//     XOR swizzle, XCD remap, 3 blocks/CU). R19 showed launch_bounds(256,4)
//     does NOT raise occupancy (HW stays at 3 blocks) -- keep (256,3).
// ---------------------------------------------------------------------------
__global__ __launch_bounds__(256, 3) void k_scores_bf16(
    const unsigned short* __restrict__ encb,  // [32768][1024] bf16
    const unsigned short* __restrict__ Wt,    // [1024 a][1024 h] bf16
    const float* __restrict__ dvec,           // [64][1024]
    const float* __restrict__ w_out,          // [1024]
    float* __restrict__ scores) {             // [64][512], pre-zeroed
  __shared__ alignas(16) unsigned short lds[2][8192];  // 2 x (A 8KB | B 8KB)
  __shared__ float sc[128];

  const int tid = threadIdx.x;
  const int wave = tid >> 6, lane = tid & 63;
  const int l15 = lane & 15, quad = lane >> 4;
  const int xcd = blockIdx.x & 7;          // HW: XCD = blockIdx % 8
  const int kb_ = blockIdx.x >> 3;
  const int mt = ((kb_ >> 3) << 3) | xcd;  // same-mt blocks -> same XCD
  const int nt = kb_ & 7;
  const int row0 = mt * 128;
  const int b = row0 >> 9;
  const int wm = (wave >> 1) * 64, wn = (wave & 1) * 64;
  const int srow = lane >> 2;         // 0..15 within staging region
  const int fsw = ((lane >> 2) & 3) ^ ((lane >> 4) & 3);
  const int skoff = (((lane & 3) ^ fsw) * 8);
  const int rchunk = ((quad ^ ((l15 & 3) ^ ((l15 >> 2) & 3))) * 8);

  if (tid < 128) sc[tid] = 0.f;

  const unsigned short* gsrc[4];
#pragma unroll
  for (int s = 0; s < 4; ++s) {
    const int g = wave * 4 + s;
    gsrc[s] = (g < 8)
        ? encb + (size_t)(row0 + g * 16 + srow) * 1024 + skoff
        : Wt + (size_t)(nt * 128 + (g - 8) * 16 + srow) * 1024 + skoff;
  }

  const f32x4 vz = {0.f, 0.f, 0.f, 0.f};
  f32x4 acc[4][4];
#pragma unroll
  for (int i = 0; i < 4; ++i)
#pragma unroll
    for (int j = 0; j < 4; ++j) acc[i][j] = vz;

#define STAGE(BUF, KK)                                              \
  do {                                                              \
    _Pragma("unroll") for (int s = 0; s < 4; ++s)                   \
        gl_lds16(gsrc[s] + (KK), &lds[BUF][(wave * 4 + s) * 512]);  \
  } while (0)

#define COMPUTE(BUF)                                                          \
  do {                                                                        \
    bf16x8 af[4], bg[4];                                                      \
    _Pragma("unroll") for (int i = 0; i < 4; ++i)                             \
        af[i] = *(const bf16x8*)(&lds[BUF][(wm + i * 16 + l15) * LSTR + rchunk]); \
    _Pragma("unroll") for (int j = 0; j < 4; ++j)                             \
        bg[j] = *(const bf16x8*)(&lds[BUF][4096 + (wn + j * 16 + l15) * LSTR + rchunk]); \
    _Pragma("unroll") for (int i = 0; i < 4; ++i)                             \
      _Pragma("unroll") for (int j = 0; j < 4; ++j)                           \
          acc[i][j] = __builtin_amdgcn_mfma_f32_16x16x32_bf16(af[i], bg[j],   \
                                                              acc[i][j], 0, 0, 0); \
  } while (0)

  STAGE(0, 0);
  __syncthreads();

#pragma unroll 1
  for (int k0 = 0; k0 < 1024; k0 += 64) {
    STAGE(1, k0 + 32);
    COMPUTE(0);
    __syncthreads();
    if (k0 + 64 < 1024) { STAGE(0, k0 + 64); }
    COMPUTE(1);
    __syncthreads();
  }
#undef STAGE
#undef COMPUTE

  float p[4][4];
#pragma unroll
  for (int i = 0; i < 4; ++i)
#pragma unroll
    for (int r = 0; r < 4; ++r) p[i][r] = 0.f;
#pragma unroll
  for (int j = 0; j < 4; ++j) {
    const int a = nt * 128 + wn + j * 16 + l15;
    const float dv = dvec[(size_t)b * 1024 + a];
    const float wo = w_out[a];
#pragma unroll
    for (int i = 0; i < 4; ++i)
#pragma unroll
      for (int r = 0; r < 4; ++r)
        p[i][r] += tanh_fast(acc[i][j][r] + dv) * wo;
  }
#pragma unroll
  for (int i = 0; i < 4; ++i)
#pragma unroll
    for (int r = 0; r < 4; ++r) {
      float v = p[i][r];
      v += __shfl_xor(v, 1);
      v += __shfl_xor(v, 2);
      v += __shfl_xor(v, 4);
      v += __shfl_xor(v, 8);
      if (l15 == 0) atomicAdd(&sc[wm + i * 16 + quad * 4 + r], v);
    }
  __syncthreads();
  if (tid < 128)
    atomicAdd(&scores[(size_t)b * 512 + (row0 & 511) + tid], sc[tid]);
}

// ---------------------------------------------------------------------------
// 3b) fp32 fallback (unchanged)
// ---------------------------------------------------------------------------
__global__ __launch_bounds__(256) void k_scores_f32(
    const float* __restrict__ enc, const unsigned short* __restrict__ Wt,
    const float* __restrict__ dvec, const float* __restrict__ w_out,
    float* __restrict__ scores) {
  __shared__ alignas(16) unsigned short lA[128 * LSTR];
  __shared__ alignas(16) unsigned short lB[128 * LSTR];
  __shared__ float sc[128];
  const int tid = threadIdx.x;
  const int wave = tid >> 6, lane = tid & 63;
  const int l15 = lane & 15, quad = lane >> 4;
  const int mt = blockIdx.x >> 2, nh = blockIdx.x & 3;
  const int row0 = mt * 128, b = row0 >> 9;
  const int wm = (wave >> 1) * 64, wn = (wave & 1) * 64;
  const int srow = lane >> 2, skoff = (lane & 3) * 8;
  if (tid < 128) sc[tid] = 0.f;
  const f32x4 vz = {0.f, 0.f, 0.f, 0.f};
#pragma unroll 1
  for (int t2 = 0; t2 < 2; ++t2) {
    const int nt = nh * 2 + t2;
    f32x4 acc[4][4];
#pragma unroll
    for (int i = 0; i < 4; ++i)
#pragma unroll
      for (int j = 0; j < 4; ++j) acc[i][j] = vz;
#pragma unroll 1
    for (int k0 = 0; k0 < 1024; k0 += 32) {
      ushort4 sa[2][2];
      uint4 vb[2];
#pragma unroll
      for (int rr = 0; rr < 2; ++rr) {
        const int r = wave * 2 + rr;
        const float* ap = enc + (size_t)(row0 + r * 16 + srow) * 1024 + k0 + skoff;
        sa[rr][0] = cvt4(*(const float4*)ap);
        sa[rr][1] = cvt4(*(const float4*)(ap + 4));
        vb[rr] = *(const uint4*)(Wt + (size_t)(nt * 128 + r * 16 + srow) * 1024 + k0 + skoff);
      }
      __syncthreads();
#pragma unroll
      for (int rr = 0; rr < 2; ++rr) {
        const int r = wave * 2 + rr;
        *(ushort4*)(lA + (r * 16 + srow) * LSTR + skoff) = sa[rr][0];
        *(ushort4*)(lA + (r * 16 + srow) * LSTR + skoff + 4) = sa[rr][1];
        *(uint4*)(lB + (r * 16 + srow) * LSTR + skoff) = vb[rr];
      }
      __syncthreads();
      bf16x8 af[4], bg[4];
#pragma unroll
      for (int i = 0; i < 4; ++i)
        af[i] = *(const bf16x8*)(lA + (wm + i * 16 + l15) * LSTR + quad * 8);
#pragma unroll
      for (int j = 0; j < 4; ++j)
        bg[j] = *(const bf16x8*)(lB + (wn + j * 16 + l15) * LSTR + quad * 8);
#pragma unroll
      for (int i = 0; i < 4; ++i)
#pragma unroll
        for (int j = 0; j < 4; ++j)
          acc[i][j] = __builtin_amdgcn_mfma_f32_16x16x32_bf16(af[i], bg[j],
                                                              acc[i][j], 0, 0, 0);
    }
    float p[4][4];
#pragma unroll
    for (int i = 0; i < 4; ++i)
#pragma unroll
      for (int r = 0; r < 4; ++r) p[i][r] = 0.f;
#pragma unroll
    for (int j = 0; j < 4; ++j) {
      const int a = nt * 128 + wn + j * 16 + l15;
      const float dv = dvec[(size_t)b * 1024 + a];
      const float wo = w_out[a];
#pragma unroll
      for (int i = 0; i < 4; ++i)
#pragma unroll
        for (int r = 0; r < 4; ++r)
          p[i][r] += tanh_fast(acc[i][j][r] + dv) * wo;
    }
#pragma unroll
    for (int i = 0; i < 4; ++i)
#pragma unroll
      for (int r = 0; r < 4; ++r) {
        float v = p[i][r];
        v += __shfl_xor(v, 1);
        v += __shfl_xor(v, 2);
        v += __shfl_xor(v, 4);
        v += __shfl_xor(v, 8);
        if (l15 == 0) atomicAdd(&sc[wm + i * 16 + quad * 4 + r], v);
      }
  }
  __syncthreads();
  if (tid < 128)
    atomicAdd(&scores[(size_t)b * 512 + (row0 & 511) + tid], sc[tid]);
}

// ---------------------------------------------------------------------------
// 4) attn (R9/R17-measured): grid 1024 = 64 b x 8 hch x 2 s-halves.
//    Full softmax per block (cheap, redundant), GEMV over 256-s half x 128-h
//    slice, writes partial plane att2[sh][b][h]. No atomics.
// ---------------------------------------------------------------------------
template <bool ABF16>
__global__ __launch_bounds__(256) void k_attn(const void* __restrict__ encv,
                                              const float* __restrict__ scores,
                                              float* __restrict__ att2) {
  const int b = blockIdx.x >> 4;
  const int hch = (blockIdx.x >> 1) & 7;
  const int sh = blockIdx.x & 1;
  const int tid = threadIdx.x;
  __shared__ float w[512];
  __shared__ float redm[4], reds[4];
  __shared__ float red[16][132];   // +4 pad

  const float s0 = scores[(size_t)b * 512 + tid];
  const float s1 = scores[(size_t)b * 512 + 256 + tid];
  float m = fmaxf(s0, s1);
#pragma unroll
  for (int off = 32; off; off >>= 1) m = fmaxf(m, __shfl_xor(m, off));
  const int wv = tid >> 6;
  if ((tid & 63) == 0) redm[wv] = m;
  __syncthreads();
  m = fmaxf(fmaxf(redm[0], redm[1]), fmaxf(redm[2], redm[3]));
  const float e0 = __builtin_amdgcn_exp2f((s0 - m) * LOG2E);
  const float e1 = __builtin_amdgcn_exp2f((s1 - m) * LOG2E);
  float sum = e0 + e1;
#pragma unroll
  for (int off = 32; off; off >>= 1) sum += __shfl_xor(sum, off);
  if ((tid & 63) == 0) reds[wv] = sum;
  __syncthreads();
  sum = reds[0] + reds[1] + reds[2] + reds[3];
  const float inv = 1.f / sum;
  w[tid] = e0 * inv;
  w[tid + 256] = e1 * inv;
  __syncthreads();

  const int sgrp = tid >> 4;        // 0..15
  const int hsub = tid & 15;        // 0..15
  const int h0 = hch * 128 + hsub * 8;
  float a[8];
#pragma unroll
  for (int j = 0; j < 8; ++j) a[j] = 0.f;
#pragma unroll 8
  for (int si = 0; si < 16; ++si) {
    const int s = sh * 256 + si * 16 + sgrp;
    const float ws_ = w[s];
    if constexpr (ABF16) {
      const uint4 v = *(const uint4*)((const unsigned short*)encv +
                                      (size_t)(b * 512 + s) * 1024 + h0);
      a[0] += ws_ * bflo(v.x); a[1] += ws_ * bfhi(v.x);
      a[2] += ws_ * bflo(v.y); a[3] += ws_ * bfhi(v.y);
      a[4] += ws_ * bflo(v.z); a[5] += ws_ * bfhi(v.z);
      a[6] += ws_ * bflo(v.w); a[7] += ws_ * bfhi(v.w);
    } else {
      const float* ep = (const float*)encv + (size_t)(b * 512 + s) * 1024 + h0;
      const float4 v0 = *(const float4*)ep;
      const float4 v1 = *(const float4*)(ep + 4);
      a[0] += ws_ * v0.x; a[1] += ws_ * v0.y;
      a[2] += ws_ * v0.z; a[3] += ws_ * v0.w;
      a[4] += ws_ * v1.x; a[5] += ws_ * v1.y;
      a[6] += ws_ * v1.z; a[7] += ws_ * v1.w;
    }
  }
#pragma unroll
  for (int j = 0; j < 8; ++j) red[sgrp][hsub * 8 + j] = a[j];
  __syncthreads();
#pragma unroll
  for (int step = 8; step >= 1; step >>= 1) {
    if (sgrp < step) {
#pragma unroll
      for (int j = 0; j < 8; ++j)
        red[sgrp][hsub * 8 + j] += red[sgrp + step][hsub * 8 + j];
    }
    __syncthreads();
  }
  if (sgrp == 0) {
    float* op = att2 + ((size_t)sh * 64 + b) * 1024 + h0;
    float4 o0 = {red[0][hsub * 8 + 0], red[0][hsub * 8 + 1],
                 red[0][hsub * 8 + 2], red[0][hsub * 8 + 3]};
    float4 o1 = {red[0][hsub * 8 + 4], red[0][hsub * 8 + 5],
                 red[0][hsub * 8 + 6], red[0][hsub * 8 + 7]};
    *(float4*)op = o0;
    *(float4*)(op + 4) = o1;
  }
}

// ---------------------------------------------------------------------------
// 5) GRU gemms (R9/R17-measured): K-eighths, grid 768, 16 partial planes.
// ---------------------------------------------------------------------------
__global__ __launch_bounds__(256) void k_gru_gemm(
    const float* __restrict__ xin,    // [64][1024]
    const float* __restrict__ att2,   // [2][64][1024] partial planes
    const float* __restrict__ states, // [64][1024]
    const float* __restrict__ W_ih,   // [3072][2048]
    const float* __restrict__ W_hh,   // [3072][1024]
    float* __restrict__ gbuf) {       // [16][64][3072] partial planes
  const int tid = threadIdx.x;
  const int wave = tid >> 6, lane = tid & 63;
  const int l15 = lane & 15, quad = lane >> 4;
  const int kk = blockIdx.x & 7;
  const int rest = blockIdx.x >> 3;   // 0..95
  const bool is_gh = rest >= 48;
  const int nt = is_gh ? rest - 48 : rest;
  const int n0 = nt * 64;
  const int KT = is_gh ? 1024 : 2048;
  const int Kh = KT >> 3;             // eighth
  const int kbase = kk * Kh;
  const float* W = is_gh ? W_hh : W_ih;
  const int plane = is_gh ? 8 + kk : kk;
  float* outp = gbuf + (size_t)plane * 64 * 3072;

  __shared__ alignas(16) unsigned short lA[64 * LSTR];
  __shared__ alignas(16) unsigned short lB[64 * LSTR];

  const f32x4 vz = {0.f, 0.f, 0.f, 0.f};
  f32x4 acc[2][2];
  acc[0][0] = vz; acc[0][1] = vz; acc[1][0] = vz; acc[1][1] = vz;

  const int arow = tid >> 2;          // 0..63
  const int achunk = (tid & 3) * 8;   // global chunk (unswizzled)
  const int fswG = ((tid >> 2) & 3) ^ ((tid >> 4) & 3);
  const int wchunk = (((tid & 3) ^ fswG) * 8);
  const int rchunkG = ((quad ^ ((l15 & 3) ^ ((l15 >> 2) & 3))) * 8);
  const int wm2 = (wave >> 1) * 32, wn2 = (wave & 1) * 32;

  float4 ra0, ra1, rb0, rb1;
  auto LOADK = [&](int kg0) {
    const int kg = kg0 + achunk;
    if (is_gh) {
      const float* ap = states + (size_t)arow * 1024 + kg;
      ra0 = *(const float4*)ap;
      ra1 = *(const float4*)(ap + 4);
    } else if (kg < 1024) {
      const float* ap = xin + (size_t)arow * 1024 + kg;
      ra0 = *(const float4*)ap;
      ra1 = *(const float4*)(ap + 4);
    } else {
      const float* p0 = att2 + (size_t)arow * 1024 + (kg - 1024);
      const float* p1 = p0 + (size_t)64 * 1024;
      const float4 x0 = *(const float4*)p0, y0 = *(const float4*)p1;
      const float4 x1 = *(const float4*)(p0 + 4), y1 = *(const float4*)(p1 + 4);
      ra0 = make_float4(x0.x + y0.x, x0.y + y0.y, x0.z + y0.z, x0.w + y0.w);
      ra1 = make_float4(x1.x + y1.x, x1.y + y1.y, x1.z + y1.z, x1.w + y1.w);
    }
    const float* wp = W + (size_t)(n0 + arow) * KT + kg;
    rb0 = *(const float4*)wp;
    rb1 = *(const float4*)(wp + 4);
  };
  LOADK(kbase);

#pragma unroll 1
  for (int k0 = 0; k0 < Kh; k0 += 32) {
    __syncthreads();
    *(ushort4*)(lA + arow * LSTR + wchunk) = cvt4(ra0);
    *(ushort4*)(lA + arow * LSTR + wchunk + 4) = cvt4(ra1);
    *(ushort4*)(lB + arow * LSTR + wchunk) = cvt4(rb0);
    *(ushort4*)(lB + arow * LSTR + wchunk + 4) = cvt4(rb1);
    __syncthreads();
    if (k0 + 32 < Kh) LOADK(kbase + k0 + 32);  // issue early; MFMA covers latency
    bf16x8 af[2], bg[2];
#pragma unroll
    for (int i = 0; i < 2; ++i)
      af[i] = *(const bf16x8*)(lA + (wm2 + i * 16 + l15) * LSTR + rchunkG);
#pragma unroll
    for (int j = 0; j < 2; ++j)
      bg[j] = *(const bf16x8*)(lB + (wn2 + j * 16 + l15) * LSTR + rchunkG);
#pragma unroll
    for (int i = 0; i < 2; ++i)
#pragma unroll
      for (int j = 0; j < 2; ++j)
        acc[i][j] = __builtin_amdgcn_mfma_f32_16x16x32_bf16(af[i], bg[j],
                                                            acc[i][j], 0, 0, 0);
  }
#pragma unroll
  for (int i = 0; i < 2; ++i)
#pragma unroll
    for (int j = 0; j < 2; ++j)
#pragma unroll
      for (int r = 0; r < 4; ++r) {
        const int m = wm2 + i * 16 + quad * 4 + r;
        const int n = n0 + wn2 + j * 16 + l15;
        outp[(size_t)m * 3072 + n] = acc[i][j][r];
      }
}

// ---------------------------------------------------------------------------
// 6) gates: sum 8 gi-planes + 8 gh-planes -> output fp32
// ---------------------------------------------------------------------------
__global__ void k_gate(const float* __restrict__ gbuf,
                       const float* __restrict__ states,
                       const float* __restrict__ b_ih,
                       const float* __restrict__ b_hh,
                       float* __restrict__ outp) {
  const int idx = blockIdx.x * 256 + threadIdx.x;  // 0..65535
  const int b = idx >> 10, h = idx & 1023;
  float gir = 0.f, giz = 0.f, gin = 0.f, ghr = 0.f, ghz = 0.f, ghn = 0.f;
#pragma unroll
  for (int p = 0; p < 8; ++p) {
    const float* gi = gbuf + ((size_t)p * 64 + b) * 3072;
    gir += gi[h]; giz += gi[1024 + h]; gin += gi[2048 + h];
    const float* gh = gbuf + ((size_t)(8 + p) * 64 + b) * 3072;
    ghr += gh[h]; ghz += gh[1024 + h]; ghn += gh[2048 + h];
  }
  const float ir = gir + b_ih[h];
  const float iz = giz + b_ih[1024 + h];
  const float in_ = gin + b_ih[2048 + h];
  const float hr = ghr + b_hh[h];
  const float hz = ghz + b_hh[1024 + h];
  const float hn = ghn + b_hh[2048 + h];
  const float r = sigmoid_fast(ir + hr);
  const float z = sigmoid_fast(iz + hz);
  const float n = tanh_fast(in_ + r * hn);
  const float hp = states[idx];
  outp[idx] = (1.f - z) * n + z * hp;
}

// ---------------------------------------------------------------------------
extern "C" void kernel_launch(void* const* d_in, const int* in_sizes, int n_in,
                              void* d_out, int out_size, void* d_ws, size_t ws_size,
                              hipStream_t stream) {
  const float* enc    = (const float*)d_in[0];
  const float* xin    = (const float*)d_in[1];
  const float* states = (const float*)d_in[2];
  const float* W_enc  = (const float*)d_in[3];
  const float* b_enc  = (const float*)d_in[4];
  const float* W_dec  = (const float*)d_in[5];
  const float* b_dec  = (const float*)d_in[6];
  const float* w_out  = (const float*)d_in[7];
  // d_in[8] = b_out: softmax-shift-invariant, unused exactly.
  const float* W_ih   = (const float*)d_in[9];
  const float* W_hh   = (const float*)d_in[10];
  const float* b_ih   = (const float*)d_in[11];
  const float* b_hh   = (const float*)d_in[12];
  float* out = (float*)d_out;

  const size_t ENC_BF16_BYTES = (size_t)32768 * 1024 * 2;  // 64 MB
  const bool use_bf16 = ws_size >= ENC_BF16_BYTES + (8u << 20);

  char* ws = (char*)d_ws;
  unsigned short* encb = (unsigned short*)ws;              // 64 MB (bf16 path)
  char* base = ws + (use_bf16 ? ENC_BF16_BYTES : 0);
  unsigned short* Wt = (unsigned short*)base;              // 2 MB (bf16)
  float* dvec    = (float*)(base + 2097152);               // 256 KB
  float* scoresb = (float*)(base + 2097152 + 262144);      // 128 KB (zeroed)
  float* att2    = (float*)(base + 2097152 + 262144 + 131072);  // 512 KB (2 planes)
  // gbuf [16][64][3072] fp32 = 12.6 MB. bf16 path: OVERLAY encb region (gru
  // runs after attn, the last encb reader; prep rewrites encb each iteration).
  float* gbuf = use_bf16 ? (float*)ws : (float*)(base + (4u << 20));

  const int prep_grid = use_bf16 ? 17184 : 800;
  k_prep<<<prep_grid, 256, 0, stream>>>(W_enc, Wt, states, W_dec, b_dec, b_enc,
                                        dvec, (float4*)scoresb, enc, encb);
  if (use_bf16) {
    k_scores_bf16<<<2048, 256, 0, stream>>>(encb, Wt, dvec, w_out, scoresb);
    k_attn<true><<<1024, 256, 0, stream>>>(encb, scoresb, att2);
  } else {
    k_scores_f32<<<1024, 256, 0, stream>>>(enc, Wt, dvec, w_out, scoresb);
    k_attn<false><<<1024, 256, 0, stream>>>(enc, scoresb, att2);
  }
  k_gru_gemm<<<768, 256, 0, stream>>>(xin, att2, states, W_ih, W_hh, gbuf);
  k_gate<<<256, 256, 0, stream>>>(gbuf, states, b_ih, b_hh, out);
}